// Round 13
// baseline (453.755 us; speedup 1.0000x reference)
//
#include <hip/hip_runtime.h>
#include <hip/hip_bf16.h>
#include <stdint.h>

typedef unsigned int u32;
typedef unsigned short u16;
typedef short short8 __attribute__((ext_vector_type(8)));
typedef float f32x4 __attribute__((ext_vector_type(4)));
typedef unsigned short u16x4 __attribute__((ext_vector_type(4)));
typedef __attribute__((address_space(1))) const u32 gu32;
typedef __attribute__((address_space(3))) u32 lu32;

#define NN 50000
#define NE 200000
#define WCT 576     // 256 fsrc | 256 res | 8 e_src | 8 e_dst | 48 pad (cols of C)

__device__ __forceinline__ float leaky(float x){ return x >= 0.f ? x : 0.2f*x; }
__device__ __forceinline__ float bf2f(u16 u){ return __uint_as_float(((u32)u)<<16); }
__device__ __forceinline__ u16 f2bf(float f){            // RNE
    u32 u = __float_as_uint(f);
    u32 r = (u + 0x7fffu + ((u>>16)&1u)) >> 16;
    return (u16)r;
}
// pack 2 floats -> 2 bf16 (truncation) in ONE v_perm_b32
__device__ __forceinline__ u32 pack_bf2(float a, float b){
    return __builtin_amdgcn_perm(__float_as_uint(b), __float_as_uint(a), 0x07060302u);
}
__device__ __forceinline__ int nt_src(int r){ return (r==0)?0:((r==3)?2:1); }
__device__ __forceinline__ int nt_dst(int r){ return (r==1)?0:((r==2)?2:1); }

// ra[r][512] = rel_emb[r] @ rel_W[r]
__global__ void k_ra(const float* __restrict__ rel_emb, const float* __restrict__ rel_W,
                     float* __restrict__ ra){
    int r = blockIdx.x;
    for (int j = threadIdx.x; j < 512; j += blockDim.x){
        float acc = 0.f;
        for (int i = 0; i < 64; i++) acc += rel_emb[r*64+i] * rel_W[(r*64+i)*512 + j];
        ra[r*512 + j] = acc;
    }
}

// Assemble WcatS: chunk-transposed bf16 layout matching linear global_load_lds staging:
//   WcatS[((r*9+tile)*32 + kc)*512 + nrow*8 + off] = W^T[n=tile*64+nrow][k=kc*8+off]
__global__ void k_wcat(const float* __restrict__ node_W, const float* __restrict__ res_W,
                       const float* __restrict__ ra, u16* __restrict__ WcatS){
    int g = blockIdx.x*blockDim.x + threadIdx.x;
    if (g >= 4*WCT*256) return;
    int r = g/147456; int rem = g%147456;
    int tile = rem/16384; int rem2 = rem%16384;
    int kc = rem2/512; int rem3 = rem2%512;
    int nrow = rem3>>3; int off = rem3&7;
    int n = tile*64 + nrow;
    int k = kc*8 + off;
    int s = nt_src(r), d = nt_dst(r);
    float v;
    if (n < 256) v = node_W[(s*256+k)*256 + n];
    else if (n < 512) v = res_W[(d*256+k)*256 + (n-256)];
    else if (n < 520){ // e_src weights: node_W[s]·ra[h, D:]
        int h = n-512; float a = 0.f;
        for (int dd = 0; dd < 32; dd++) a += node_W[(s*256+k)*256 + h*32+dd] * ra[r*512 + h*64+32+dd];
        v = a;
    } else if (n < 528){ // e_dst weights: node_W[d]·ra[h, :D]
        int h = n-520; float a = 0.f;
        for (int dd = 0; dd < 32; dd++) a += node_W[(d*256+k)*256 + h*32+dd] * ra[r*512 + h*64+dd];
        v = a;
    } else v = 0.f;
    WcatS[g] = f2bf(v);
}

// MFMA GEMM, fat blocks: one 512-thread block = 128-row strip x ALL 576 N.
// A K-resident in registers; B async-staged via global_load_lds, double-buffered.
// ONE barrier per tile: stores issued AFTER the barrier (overlap next tile's
// compute, drained at the next barrier). No LDS epilogue staging.
__launch_bounds__(512, 4)
__global__ void k_gemm(const float* __restrict__ feat, const u16* __restrict__ WcatS,
                       const float* __restrict__ res_b,
                       u16* __restrict__ fsrc, u16* __restrict__ resb,
                       float* __restrict__ e_comb){
    __shared__ uint4 lsB[4096];          // 2 x 32KB B double buffer
    const short8* lsB8 = (const short8*)lsB;

    int r = blockIdx.y;
    int row0 = blockIdx.x*128;
    const float* A = feat + (size_t)r*NN*256;
    const u16*   W = WcatS + (size_t)r*9*16384;

    int t = threadIdx.x;
    int w = t>>6, l = t&63;
    int wm = (w>>1)*32, wn = (w&1)*32;   // 8 waves: 4 row-bands x 2 col-halves
    int li = l & 15, lg = l >> 4;

    // ---- A fragments: direct global -> registers, K-resident (64 VGPR/lane)
    short8 afr[2][8];
    #pragma unroll
    for (int mt = 0; mt < 2; mt++){
        int grow = row0 + wm + mt*16 + li; if (grow > NN-1) grow = NN-1;
        const float* ap = A + (size_t)grow*256 + lg*8;
        #pragma unroll
        for (int kk = 0; kk < 8; kk++){
            f32x4 x = __builtin_nontemporal_load((const f32x4*)(ap + kk*32));
            f32x4 y = __builtin_nontemporal_load((const f32x4*)(ap + kk*32 + 4));
            short8 f;
            ((u32*)&f)[0] = pack_bf2(x.x, x.y);
            ((u32*)&f)[1] = pack_bf2(x.z, x.w);
            ((u32*)&f)[2] = pack_bf2(y.x, y.y);
            ((u32*)&f)[3] = pack_bf2(y.z, y.w);
            afr[mt][kk] = f;
        }
    }

    // ---- prologue: stage tile 0 into buf 0 (async direct-to-LDS); 4 chunks/thread
    #pragma unroll
    for (int i = 0; i < 4; i++){
        int chunk = i*512 + t;
        __builtin_amdgcn_global_load_lds((gu32*)(W + (size_t)chunk*8),
                                         (lu32*)((char*)lsB + chunk*16), 16, 0, 0);
    }
    __syncthreads();

    int d = nt_dst(r);
    for (int T = 0; T < 8; T++){
        int cur = T & 1;
        // issue async stage of tile T+1 into the other buffer (flies under MFMA)
        {
            const u16* tb = W + (size_t)(T+1)*16384;
            char* lb = (char*)lsB + (cur^1)*32768;
            #pragma unroll
            for (int i = 0; i < 4; i++){
                int chunk = i*512 + t;
                __builtin_amdgcn_global_load_lds((gu32*)(tb + (size_t)chunk*8),
                                                 (lu32*)(lb + chunk*16), 16, 0, 0);
            }
        }
        // compute tile T from buf[cur]
        f32x4 acc[2][2] = {};
        #pragma unroll
        for (int kk = 0; kk < 8; kk++){
            short8 bfr[2];
            #pragma unroll
            for (int nt = 0; nt < 2; nt++)
                bfr[nt] = lsB8[cur*2048 + (kk*4+lg)*64 + wn + nt*16 + li];
            #pragma unroll
            for (int mt = 0; mt < 2; mt++)
                #pragma unroll
                for (int nt = 0; nt < 2; nt++)
                    acc[mt][nt] = __builtin_amdgcn_mfma_f32_16x16x32_bf16(afr[mt][kk], bfr[nt], acc[mt][nt], 0,0,0);
        }
        float bias[2] = {0.f, 0.f};
        if (T >= 4){
            bias[0] = res_b[d*256 + (T-4)*64 + wn + li];
            bias[1] = res_b[d*256 + (T-4)*64 + wn + 16 + li];
        }
        __syncthreads();   // tile T+1 landed; all waves done reading buf[cur]
        // direct C stores (overlap next tile's compute; drained at next barrier).
        // per (mt,qq): two 32B half-lines (nt=0,1) = one full 64B line per row.
        u16* base = (T < 4) ? fsrc : resb;
        int cb = (T & 3)*64 + wn;
        #pragma unroll
        for (int mt = 0; mt < 2; mt++)
            #pragma unroll
            for (int qq = 0; qq < 4; qq++){
                int row = row0 + wm + mt*16 + lg*4 + qq;
                if (row < NN){
                    size_t off = ((size_t)r*NN + row)*256 + cb;
                    base[off + li]      = f2bf(acc[mt][0][qq] + bias[0]);
                    base[off + 16 + li] = f2bf(acc[mt][1][qq] + bias[1]);
                }
            }
    }

    // ---- tile 8: e-columns 512..527 (nrow 0..15 of tile 8, in buf 0) -> e_comb
    if (wn == 0){
        f32x4 acc[2] = {};
        #pragma unroll
        for (int kk = 0; kk < 8; kk++){
            short8 bfr = lsB8[(kk*4+lg)*64 + li];
            #pragma unroll
            for (int mt = 0; mt < 2; mt++)
                acc[mt] = __builtin_amdgcn_mfma_f32_16x16x32_bf16(afr[mt][kk], bfr, acc[mt], 0,0,0);
        }
        #pragma unroll
        for (int mt = 0; mt < 2; mt++)
            #pragma unroll
            for (int qq = 0; qq < 4; qq++){
                int row = row0 + wm + mt*16 + lg*4 + qq;
                if (row < NN)
                    e_comb[((size_t)r*NN + row)*16 + li] = acc[mt][qq];
            }
    }
}

// ---- CSR build: count -> hierarchical scan -> scatter ----

__global__ void k_count(const int* __restrict__ dst_idx, u32* __restrict__ cnt){
    int r = blockIdx.y; int e = blockIdx.x*256 + threadIdx.x;
    if (e >= NE) return;
    atomicAdd(&cnt[r*NN + dst_idx[r*NE+e]], 1u);
}

__global__ void k_scan1(const u32* __restrict__ cnt, u32* __restrict__ bsum){
    int r = blockIdx.y, b = blockIdx.x;
    int i = b*256 + threadIdx.x;
    u32 v = (i < NN) ? cnt[r*NN+i] : 0u;
    #pragma unroll
    for (int off = 1; off < 64; off <<= 1) v += __shfl_xor(v, off, 64);
    __shared__ u32 wsum[4];
    int lane = threadIdx.x & 63, w = threadIdx.x >> 6;
    if (lane == 0) wsum[w] = v;
    __syncthreads();
    if (threadIdx.x == 0) bsum[r*256 + b] = wsum[0]+wsum[1]+wsum[2]+wsum[3];
}

__device__ __forceinline__ u32 block_scan_incl(u32 v){
    __shared__ u32 wsum[4];
    int lane = threadIdx.x & 63, w = threadIdx.x >> 6;
    #pragma unroll
    for (int off = 1; off < 64; off <<= 1){
        u32 t = __shfl_up(v, off, 64);
        if (lane >= off) v += t;
    }
    if (lane == 63) wsum[w] = v;
    __syncthreads();
    u32 add = 0;
    #pragma unroll
    for (int k = 0; k < 4; k++) if (k < w) add += wsum[k];
    return v + add;
}

__global__ void k_scan2(u32* __restrict__ bsum){
    int r = blockIdx.x;
    u32 v = bsum[r*256 + threadIdx.x];
    u32 incl = block_scan_incl(v);
    bsum[r*256 + threadIdx.x] = incl - v;
}

__global__ void k_scan3(const u32* __restrict__ cnt, const u32* __restrict__ bsum,
                        u32* __restrict__ row_ptr){
    int r = blockIdx.y, b = blockIdx.x;
    int i = b*256 + threadIdx.x;
    u32 v = (i < NN) ? cnt[r*NN+i] : 0u;
    u32 incl = block_scan_incl(v);
    if (i < NN) row_ptr[r*(NN+1) + i + 1] = bsum[r*256 + b] + incl;
    if (b == 0 && threadIdx.x == 0) row_ptr[r*(NN+1)] = 0u;
}

// per edge: pos in dst bucket; payload = src + 8 PRE-EXPONENTIATED logits
__global__ void k_scatter(const int* __restrict__ src_idx, const int* __restrict__ dst_idx,
                          const float* __restrict__ e_comb,
                          const u32* __restrict__ row_ptr, u32* __restrict__ cnt2,
                          u32* __restrict__ src_pack, float* __restrict__ e_pack){
    int r = blockIdx.y; int e = blockIdx.x*256 + threadIdx.x;
    if (e >= NE) return;
    int s = src_idx[r*NE+e], d = dst_idx[r*NE+e];
    u32 pos = row_ptr[r*(NN+1)+d] + atomicAdd(&cnt2[r*NN+d], 1u);
    src_pack[r*NE + pos] = (u32)s;
    const f32x4* es = (const f32x4*)(e_comb + (size_t)(r*NN+s)*16);
    const f32x4* ed = (const f32x4*)(e_comb + (size_t)(r*NN+d)*16 + 8);
    f32x4 s0 = es[0], s1 = es[1], d0 = ed[0], d1 = ed[1];
    f32x4 w0, w1;
    w0.x = __expf(leaky(s0.x+d0.x)); w0.y = __expf(leaky(s0.y+d0.y));
    w0.z = __expf(leaky(s0.z+d0.z)); w0.w = __expf(leaky(s0.w+d0.w));
    w1.x = __expf(leaky(s1.x+d1.x)); w1.y = __expf(leaky(s1.y+d1.y));
    w1.z = __expf(leaky(s1.z+d1.z)); w1.w = __expf(leaky(s1.w+d1.w));
    f32x4* ep = (f32x4*)(e_pack + ((size_t)(r*NE)+pos)*8);
    ep[0] = w0; ep[1] = w1;
}

// Shared aggregation core: per (node, relation) wave -> conv row (c0..c3 per lane).
__device__ __forceinline__ void agg_core(int n, int r, int l, int h,
                                         const u32* __restrict__ row_ptr,
                                         const u32* __restrict__ src_pack,
                                         const float* __restrict__ e_pack,
                                         const u16* __restrict__ fsrc,
                                         const u16* __restrict__ resb,
                                         const float* __restrict__ res_alpha,
                                         float& c0, float& c1, float& c2, float& c3){
    u32 p0 = row_ptr[r*(NN+1)+n];
    u32 p1 = row_ptr[r*(NN+1)+n+1];
    int deg = (int)(p1 - p0);

    // phase 1: plain sum of pre-exponentiated weights
    float s = 0.f;
    for (int i = (l>>3); i < deg; i += 8)
        s += e_pack[((size_t)(r*NE) + p0 + i)*8 + (l&7)];
    #pragma unroll
    for (int msk = 8; msk < 64; msk <<= 1)
        s += __shfl_xor(s, msk, 64);
    float sh = __shfl(s, h, 64);
    float inv_sh = (deg > 0) ? 1.0f / sh : 0.f;

    // phase 2: gather-accumulate; src preloaded + shfl-broadcast, 4-way unroll
    float a0=0.f, a1=0.f, a2=0.f, a3=0.f;
    const size_t ebase = (size_t)r*NE + p0;
    const u16* fbase = fsrc + (size_t)r*NN*256;
    for (int base = 0; base < deg; base += 64){
        int rem = deg - base; if (rem > 64) rem = 64;
        u32 my_src = 0;
        if (l < rem) my_src = src_pack[ebase + base + l];
        int i = 0;
        for (; i+4 <= rem; i += 4){
            u32 s0 = __shfl(my_src, i, 64);
            u32 s1 = __shfl(my_src, i+1, 64);
            u32 s2 = __shfl(my_src, i+2, 64);
            u32 s3 = __shfl(my_src, i+3, 64);
            float ex0 = e_pack[(ebase + base + i)*8 + h];
            float ex1 = e_pack[(ebase + base + i + 1)*8 + h];
            float ex2 = e_pack[(ebase + base + i + 2)*8 + h];
            float ex3 = e_pack[(ebase + base + i + 3)*8 + h];
            ushort4 f0 = *(const ushort4*)(fbase + (size_t)s0*256 + l*4);
            ushort4 f1 = *(const ushort4*)(fbase + (size_t)s1*256 + l*4);
            ushort4 f2 = *(const ushort4*)(fbase + (size_t)s2*256 + l*4);
            ushort4 f3 = *(const ushort4*)(fbase + (size_t)s3*256 + l*4);
            float w0 = ex0*inv_sh, w1 = ex1*inv_sh, w2 = ex2*inv_sh, w3 = ex3*inv_sh;
            a0 += bf2f(f0.x)*w0 + bf2f(f1.x)*w1 + bf2f(f2.x)*w2 + bf2f(f3.x)*w3;
            a1 += bf2f(f0.y)*w0 + bf2f(f1.y)*w1 + bf2f(f2.y)*w2 + bf2f(f3.y)*w3;
            a2 += bf2f(f0.z)*w0 + bf2f(f1.z)*w1 + bf2f(f2.z)*w2 + bf2f(f3.z)*w3;
            a3 += bf2f(f0.w)*w0 + bf2f(f1.w)*w1 + bf2f(f2.w)*w2 + bf2f(f3.w)*w3;
        }
        for (; i < rem; i++){
            u32 s0 = __shfl(my_src, i, 64);
            float w0 = e_pack[(ebase + base + i)*8 + h]*inv_sh;
            ushort4 f0 = *(const ushort4*)(fbase + (size_t)s0*256 + l*4);
            a0 += bf2f(f0.x)*w0; a1 += bf2f(f0.y)*w0; a2 += bf2f(f0.z)*w0; a3 += bf2f(f0.w)*w0;
        }
    }

    int d = nt_dst(r);
    float alpha = 1.f/(1.f + __expf(-res_alpha[d]));
    float beta = 1.f - alpha;
    u16x4 rv = __builtin_nontemporal_load((const u16x4*)(resb + ((size_t)r*NN+n)*256 + l*4));
    c0 = fmaxf(a0,0.f)*alpha + bf2f(rv.x)*beta;
    c1 = fmaxf(a1,0.f)*alpha + bf2f(rv.y)*beta;
    c2 = fmaxf(a2,0.f)*alpha + bf2f(rv.z)*beta;
    c3 = fmaxf(a3,0.f)*alpha + bf2f(rv.w)*beta;
}

// Single-relation pass (rel 1, 2): per-wave node, direct out write.
// Per-pass working set ~110 MB -> gather table L3-resident.
__launch_bounds__(256)
__global__ void k_aggr(const u32* __restrict__ row_ptr, const u32* __restrict__ src_pack,
                       const float* __restrict__ e_pack, const u16* __restrict__ fsrc,
                       const u16* __restrict__ resb, const float* __restrict__ res_alpha,
                       float* __restrict__ out, int r){
    int n = blockIdx.x*4 + (threadIdx.x >> 6);
    if (n >= NN) return;
    int l = threadIdx.x & 63;
    float c0, c1, c2, c3;
    agg_core(n, r, l, l>>3, row_ptr, src_pack, e_pack, fsrc, resb, res_alpha, c0, c1, c2, c3);
    f32x4 o = {c0, c1, c2, c3};
    __builtin_nontemporal_store(o, (f32x4*)(out + ((size_t)r*NN+n)*256 + l*4));
}

// Pass A: rel 0 -> conv0 stored bf16 into tmp (fsrc[1]'s dead slot).
__launch_bounds__(256)
__global__ void k_aggA(const u32* __restrict__ row_ptr, const u32* __restrict__ src_pack,
                       const float* __restrict__ e_pack, const u16* __restrict__ fsrc,
                       const u16* __restrict__ resb, const float* __restrict__ res_alpha,
                       u16* __restrict__ tmp0){
    int n = blockIdx.x*4 + (threadIdx.x >> 6);
    if (n >= NN) return;
    int l = threadIdx.x & 63;
    float c0, c1, c2, c3;
    agg_core(n, 0, l, l>>3, row_ptr, src_pack, e_pack, fsrc, resb, res_alpha, c0, c1, c2, c3);
    u16x4 o = {f2bf(c0), f2bf(c1), f2bf(c2), f2bf(c3)};
    *(u16x4*)(tmp0 + (size_t)n*256 + l*4) = o;
}

// Pass B: rel 3 + cross-attention (group {0,3}); reads conv0 from tmp, writes out0 & out3.
__launch_bounds__(256)
__global__ void k_aggB(const u32* __restrict__ row_ptr, const u32* __restrict__ src_pack,
                       const float* __restrict__ e_pack, const u16* __restrict__ fsrc,
                       const u16* __restrict__ resb, const float* __restrict__ res_alpha,
                       const u16* __restrict__ tmp0, const float* __restrict__ cross_attn,
                       float* __restrict__ out){
    int n = blockIdx.x*4 + (threadIdx.x >> 6);
    if (n >= NN) return;
    int l = threadIdx.x & 63;
    int h = l >> 3;
    float b0, b1, b2, b3;   // conv3
    agg_core(n, 3, l, h, row_ptr, src_pack, e_pack, fsrc, resb, res_alpha, b0, b1, b2, b3);
    u16x4 tv = *(const u16x4*)(tmp0 + (size_t)n*256 + l*4);
    float a0 = bf2f(tv.x), a1 = bf2f(tv.y), a2 = bf2f(tv.z), a3 = bf2f(tv.w); // conv0

    const float* ca0 = cross_attn;            // relation 0 weights
    const float* ca3 = cross_attn + 3*256;    // relation 3 weights
    float w00 = a0*ca0[l*4+0] + a1*ca0[l*4+1] + a2*ca0[l*4+2] + a3*ca0[l*4+3]; // conv0·ca0
    float w30 = b0*ca0[l*4+0] + b1*ca0[l*4+1] + b2*ca0[l*4+2] + b3*ca0[l*4+3]; // conv3·ca0
    float w03 = a0*ca3[l*4+0] + a1*ca3[l*4+1] + a2*ca3[l*4+2] + a3*ca3[l*4+3]; // conv0·ca3
    float w33 = b0*ca3[l*4+0] + b1*ca3[l*4+1] + b2*ca3[l*4+2] + b3*ca3[l*4+3]; // conv3·ca3
    #pragma unroll
    for (int msk = 1; msk < 8; msk <<= 1){
        w00 += __shfl_xor(w00, msk, 64);
        w30 += __shfl_xor(w30, msk, 64);
        w03 += __shfl_xor(w03, msk, 64);
        w33 += __shfl_xor(w33, msk, 64);
    }
    // out0: softmax over {leaky(w00), leaky(w30)}
    float g0 = leaky(w00), g3 = leaky(w30);
    float mm = fmaxf(g0, g3);
    float e0 = __expf(g0-mm), e3 = __expf(g3-mm);
    float inv = 1.f/(e0+e3);
    float u0 = e0*inv, u3 = e3*inv;
    f32x4 o0 = {u0*a0 + u3*b0, u0*a1 + u3*b1, u0*a2 + u3*b2, u0*a3 + u3*b3};
    __builtin_nontemporal_store(o0, (f32x4*)(out + (size_t)n*256 + l*4));
    // out3: softmax over {leaky(w03), leaky(w33)}
    float q0 = leaky(w03), q3 = leaky(w33);
    float mq = fmaxf(q0, q3);
    float v0 = __expf(q0-mq), v3 = __expf(q3-mq);
    float iv = 1.f/(v0+v3);
    v0 *= iv; v3 *= iv;
    f32x4 o3 = {v0*a0 + v3*b0, v0*a1 + v3*b1, v0*a2 + v3*b2, v0*a3 + v3*b3};
    __builtin_nontemporal_store(o3, (f32x4*)(out + ((size_t)3*NN+n)*256 + l*4));
}

__global__ void k_relout(const float* __restrict__ rel_emb, const float* __restrict__ prop_W,
                         const float* __restrict__ prop_b, float* __restrict__ out){
    int r = blockIdx.x; int o = threadIdx.x;
    float acc = prop_b[r*256 + o];
    for (int i = 0; i < 64; i++) acc += rel_emb[r*64+i] * prop_W[(r*64+i)*256 + o];
    out[(size_t)4*NN*256 + r*256 + o] = acc;
}

extern "C" void kernel_launch(void* const* d_in, const int* in_sizes, int n_in,
                              void* d_out, int out_size, void* d_ws, size_t ws_size,
                              hipStream_t stream){
    const float* feat      = (const float*)d_in[0];
    const float* rel_emb   = (const float*)d_in[1];
    const float* node_W    = (const float*)d_in[2];
    const float* rel_W     = (const float*)d_in[3];
    const float* res_W     = (const float*)d_in[4];
    const float* res_b     = (const float*)d_in[5];
    const float* res_alpha = (const float*)d_in[6];
    const float* cross_attn= (const float*)d_in[7];
    const float* prop_W    = (const float*)d_in[8];
    const float* prop_b    = (const float*)d_in[9];
    const int* src_idx     = (const int*)d_in[10];
    const int* dst_idx     = (const int*)d_in[11];
    float* out = (float*)d_out;

    char* ws = (char*)d_ws;
    u32*   cnt     = (u32*)  (ws);                 //    800,000 B (4,NN)
    u32*   cnt2    = (u32*)  (ws + 800000);        //    800,000 B (4,NN)
    u32*   bsum    = (u32*)  (ws + 1600000);       //      4,096 B (4,256)
    u32*   row_ptr = (u32*)  (ws + 1604096);       //    800,016 B (4,NN+1)
    float* ra      = (float*)(ws + 2404112);       //      8,192 B (4,512)
    u16*   WcatS   = (u16*)  (ws + 2412304);       //  1,179,648 B (4,9,32,64,8) bf16
    float* e_comb  = (float*)(ws + 3591952);       // 12,800,000 B (4,NN,16) [src|dst]
    u32*   src_pack= (u32*)  (ws + 16391952);      //  3,200,000 B (4,NE)
    float* e_pack  = (float*)(ws + 19591952);      // 25,600,000 B (4,NE,8)
    u16*   fsrc    = (u16*)  (ws + 45191952);      //102,400,000 B (4,NN,256) bf16
    u16*   resb    = (u16*)  (ws + 147591952);     //102,400,000 B (4,NN,256) bf16
    // total: 249,991,952 B
    u16*   tmp0    = fsrc + (size_t)NN*256;        // fsrc[1]'s slot, dead after rel-1 pass

    hipMemsetAsync(cnt, 0, 1604096, stream);  // cnt + cnt2 + bsum

    k_ra<<<4, 256, 0, stream>>>(rel_emb, rel_W, ra);
    k_wcat<<<(4*WCT*256)/256, 256, 0, stream>>>(node_W, res_W, ra, WcatS);
    dim3 gg((NN+127)/128, 4);
    k_gemm<<<gg, 512, 0, stream>>>(feat, WcatS, res_b, fsrc, resb, e_comb);

    dim3 geg((NE+255)/256, 4);
    k_count<<<geg, 256, 0, stream>>>(dst_idx, cnt);
    dim3 gsc((NN+255)/256, 4);
    k_scan1<<<gsc, 256, 0, stream>>>(cnt, bsum);
    k_scan2<<<4, 256, 0, stream>>>(bsum);
    k_scan3<<<gsc, 256, 0, stream>>>(cnt, bsum, row_ptr);
    k_scatter<<<geg, 256, 0, stream>>>(src_idx, dst_idx, e_comb, row_ptr, cnt2,
                                       src_pack, e_pack);
    int gag = (NN+3)/4;
    k_aggr<<<gag, 256, 0, stream>>>(row_ptr, src_pack, e_pack, fsrc, resb, res_alpha, out, 1);
    k_aggr<<<gag, 256, 0, stream>>>(row_ptr, src_pack, e_pack, fsrc, resb, res_alpha, out, 2);
    k_aggA<<<gag, 256, 0, stream>>>(row_ptr, src_pack, e_pack, fsrc, resb, res_alpha, tmp0);
    k_aggB<<<gag, 256, 0, stream>>>(row_ptr, src_pack, e_pack, fsrc, resb, res_alpha,
                                    tmp0, cross_attn, out);
    k_relout<<<4, 256, 0, stream>>>(rel_emb, prop_W, prop_b, out);
}